// Round 1
// baseline (680.943 us; speedup 1.0000x reference)
//
#include <hip/hip_runtime.h>
#include <hip/hip_bf16.h>

// GraphFusion: 3-layer GNN, B=4 N=256 D=128 E=64.
// Algebraic restructuring (exact):
//   eh   = relu(P1_i + P2_j)            P1 = x@w_top + eb1, P2 = x@w_bot
//   mh   = relu(P3_i + eh@W2)           W2 = ew2@mw_bot (precomputed),
//                                       P3 = x@mw_top + mb1 + eb2@mw_bot
//   s_i  = sum_j adj_ij * mh_ij         (fold adjacency BEFORE mw2)
//   msg_i= s_i@mw2 + (sum_j adj_ij)*mb2
//   x    = LN(x + u2(relu(u1(cat(x,msg)))))

constexpr int cB = 4, cN = 256, cD = 128, cE = 64, cL = 3, cH = 256; // cH = 2D
constexpr int JT = 64;                                              // j-chunk
#define LN_EPSF 1e-5f

// ---- precompute W2[l][f][h] = sum_e ew2[l][f][e]*mw_bot[l][e][h]; BS2 = eb2@mw_bot
__global__ __launch_bounds__(256) void kW(const float* __restrict__ ew2,
                                          const float* __restrict__ eb2,
                                          const float* __restrict__ mw1,
                                          float* __restrict__ W2,
                                          float* __restrict__ BS2) {
    int l = blockIdx.x, h = threadIdx.x;
    const float* ew2l = ew2 + l * cE * cE;
    const float* eb2l = eb2 + l * cE;
    const float* mbot = mw1 + l * (cD + cE) * cH + cD * cH; // rows D..D+E-1
    float acc[cE];
#pragma unroll
    for (int f = 0; f < cE; ++f) acc[f] = 0.f;
    float bacc = 0.f;
    for (int e = 0; e < cE; ++e) {
        float m = mbot[e * cH + h];       // coalesced across h
        bacc += eb2l[e] * m;
#pragma unroll
        for (int f = 0; f < cE; ++f) acc[f] += ew2l[f * cE + e] * m; // uniform scalar
    }
    float* W2l = W2 + l * cE * cH;
#pragma unroll
    for (int f = 0; f < cE; ++f) W2l[f * cH + h] = acc[f];
    BS2[l * cH + h] = bacc;
}

// ---- per-(b,n) precompute P1, P2, P3 from current x. block = 384 (6 waves)
__global__ __launch_bounds__(384) void kA(const float* __restrict__ x,
                                          const float* __restrict__ ew1,
                                          const float* __restrict__ eb1,
                                          const float* __restrict__ mw1,
                                          const float* __restrict__ mb1,
                                          const float* __restrict__ bs2,
                                          float* __restrict__ P1,
                                          float* __restrict__ P2,
                                          float* __restrict__ P3, int l) {
    __shared__ float xs[cD];
    int bn = blockIdx.x, t = threadIdx.x;
    if (t < cD) xs[t] = x[bn * cD + t];
    __syncthreads();
    const float* ew1l = ew1 + l * 2 * cD * cE;
    const float* mw1l = mw1 + l * (cD + cE) * cH;
    if (t < cE) {                       // wave 0: P1 (+eb1 folded)
        float acc = eb1[l * cE + t];
        for (int d = 0; d < cD; ++d) acc += xs[d] * ew1l[d * cE + t];
        P1[bn * cE + t] = acc;
    } else if (t < 2 * cE) {            // wave 1: P2
        int e = t - cE;
        float acc = 0.f;
        for (int d = 0; d < cD; ++d) acc += xs[d] * ew1l[(cD + d) * cE + e];
        P2[bn * cE + e] = acc;
    } else {                            // waves 2-5: P3 (+mb1 +bias2 folded)
        int h = t - 2 * cE;
        float acc = mb1[l * cH + h] + bs2[l * cH + h];
        for (int d = 0; d < cD; ++d) acc += xs[d] * mw1l[d * cH + h];
        P3[bn * cH + h] = acc;
    }
}

// ---- hot kernel: per (b,i): s = sum_j adj*relu(P3_i + relu(P1_i+P2_j)@W2); msg = s@mw2
__global__ __launch_bounds__(256) void kB(const float* __restrict__ P1,
                                          const float* __restrict__ P2,
                                          const float* __restrict__ P3,
                                          const float* __restrict__ adj,
                                          const float* __restrict__ W2,
                                          const float* __restrict__ mw2,
                                          const float* __restrict__ mb2,
                                          float* __restrict__ MSG, int l) {
    __shared__ float sP1[cE];
    __shared__ float sEH[JT][cE];
    __shared__ float sAdj[JT];
    __shared__ float sS[cH];
    int bn = blockIdx.x, t = threadIdx.x;
    int b = bn >> 8; // bn / cN

    if (t < cE) sP1[t] = P1[bn * cE + t];

    // thread t owns output column h=t; W2 column lives in 64 VGPRs
    float wreg[cE];
    const float* W2l = W2 + l * cE * cH;
#pragma unroll
    for (int f = 0; f < cE; ++f) wreg[f] = W2l[f * cH + t]; // coalesced
    float p3h = P3[bn * cH + t];
    float s = 0.f, asum = 0.f;
    __syncthreads();

    for (int jc = 0; jc < cN; jc += JT) {
        if (t < JT) sAdj[t] = adj[bn * cN + jc + t];
#pragma unroll
        for (int k = 0; k < (JT * cE) / 256; ++k) {   // stage EH chunk
            int idx = k * 256 + t;
            int j = idx >> 6, f = idx & 63;
            float v = sP1[f] + P2[(b * cN + jc + j) * cE + f];
            sEH[j][f] = v > 0.f ? v : 0.f;
        }
        __syncthreads();
#pragma unroll 2
        for (int j = 0; j < JT; ++j) {
            const float4* er = (const float4*)(&sEH[j][0]); // broadcast reads
            float a0 = 0.f, a1 = 0.f, a2 = 0.f, a3 = 0.f;
#pragma unroll
            for (int f4 = 0; f4 < cE / 4; ++f4) {
                float4 ev = er[f4];
                a0 += ev.x * wreg[4 * f4 + 0];
                a1 += ev.y * wreg[4 * f4 + 1];
                a2 += ev.z * wreg[4 * f4 + 2];
                a3 += ev.w * wreg[4 * f4 + 3];
            }
            float mh = p3h + (a0 + a1) + (a2 + a3);
            mh = mh > 0.f ? mh : 0.f;
            float a = sAdj[j];
            s += a * mh;
            asum += a;
        }
        __syncthreads();
    }
    sS[t] = s;
    __syncthreads();
    if (t < cD) {
        const float* mw2l = mw2 + l * cH * cD;
        float acc = asum * mb2[l * cD + t];
        for (int h = 0; h < cH; ++h) acc += sS[h] * mw2l[h * cD + t];
        MSG[bn * cD + t] = acc;
    }
}

// ---- update network + residual + LayerNorm (in-place on x; mirrors to out on last layer)
__global__ __launch_bounds__(256) void kC(float* __restrict__ x,
                                          const float* __restrict__ MSG,
                                          const float* __restrict__ uw1,
                                          const float* __restrict__ ub1,
                                          const float* __restrict__ uw2,
                                          const float* __restrict__ ub2,
                                          const float* __restrict__ lng,
                                          const float* __restrict__ lnb,
                                          float* __restrict__ out, int l, int last) {
    __shared__ float uin[cH];
    __shared__ float uh[cH];
    __shared__ float rs1[4], rs2[4];
    int bn = blockIdx.x, t = threadIdx.x;
    uin[t] = (t < cD) ? x[bn * cD + t] : MSG[bn * cD + (t - cD)];
    __syncthreads();
    const float* uw1l = uw1 + l * cH * cH;
    float acc = ub1[l * cH + t];
    for (int k = 0; k < cH; ++k) acc += uin[k] * uw1l[k * cH + t];
    uh[t] = acc > 0.f ? acc : 0.f;
    __syncthreads();
    float y = 0.f;
    if (t < cD) {
        const float* uw2l = uw2 + l * cH * cD;
        float a2 = ub2[l * cD + t];
        for (int k = 0; k < cH; ++k) a2 += uh[k] * uw2l[k * cD + t];
        y = uin[t] + a2; // residual
    }
    // LayerNorm over 128 values held by threads 0..127 (waves 2,3 contribute zeros)
    float s1 = y, s2 = y * y;
#pragma unroll
    for (int o = 1; o < 64; o <<= 1) { s1 += __shfl_xor(s1, o); s2 += __shfl_xor(s2, o); }
    if ((t & 63) == 0) { rs1[t >> 6] = s1; rs2[t >> 6] = s2; }
    __syncthreads();
    float tot = rs1[0] + rs1[1] + rs1[2] + rs1[3];
    float tq  = rs2[0] + rs2[1] + rs2[2] + rs2[3];
    float mu  = tot * (1.f / cD);
    float var = tq * (1.f / cD) - mu * mu;
    float inv = rsqrtf(var + LN_EPSF);
    if (t < cD) {
        float res = (y - mu) * inv * lng[l * cD + t] + lnb[l * cD + t];
        x[bn * cD + t] = res;
        if (last) out[bn * cD + t] = res;
    }
}

extern "C" void kernel_launch(void* const* d_in, const int* in_sizes, int n_in,
                              void* d_out, int out_size, void* d_ws, size_t ws_size,
                              hipStream_t stream) {
    (void)in_sizes; (void)n_in; (void)out_size; (void)ws_size;
    const float* nf  = (const float*)d_in[0];
    const float* adj = (const float*)d_in[1];
    const float* ew1 = (const float*)d_in[2];
    const float* eb1 = (const float*)d_in[3];
    const float* ew2 = (const float*)d_in[4];
    const float* eb2 = (const float*)d_in[5];
    const float* mw1 = (const float*)d_in[6];
    const float* mb1 = (const float*)d_in[7];
    const float* mw2 = (const float*)d_in[8];
    const float* mb2 = (const float*)d_in[9];
    const float* uw1 = (const float*)d_in[10];
    const float* ub1 = (const float*)d_in[11];
    const float* uw2 = (const float*)d_in[12];
    const float* ub2 = (const float*)d_in[13];
    const float* lng = (const float*)d_in[14];
    const float* lnb = (const float*)d_in[15];
    float* out = (float*)d_out;

    float* xbuf = (float*)d_ws;                 // B*N*D
    float* P1   = xbuf + cB * cN * cD;          // B*N*E
    float* P2   = P1   + cB * cN * cE;          // B*N*E
    float* P3   = P2   + cB * cN * cE;          // B*N*2D
    float* MSG  = P3   + cB * cN * cH;          // B*N*D
    float* W2   = MSG  + cB * cN * cD;          // L*E*2D
    float* BS2  = W2   + cL * cE * cH;          // L*2D
    // total ~2.82 MB of d_ws

    hipMemcpyAsync(xbuf, nf, cB * cN * cD * sizeof(float),
                   hipMemcpyDeviceToDevice, stream);
    kW<<<cL, 256, 0, stream>>>(ew2, eb2, mw1, W2, BS2);
    for (int l = 0; l < cL; ++l) {
        kA<<<cB * cN, 384, 0, stream>>>(xbuf, ew1, eb1, mw1, mb1, BS2, P1, P2, P3, l);
        kB<<<cB * cN, 256, 0, stream>>>(P1, P2, P3, adj, W2, mw2, mb2, MSG, l);
        kC<<<cB * cN, 256, 0, stream>>>(xbuf, MSG, uw1, ub1, uw2, ub2, lng, lnb,
                                        out, l, l == cL - 1);
    }
}

// Round 3
// 181.542 us; speedup vs baseline: 3.7509x; 3.7509x over previous
//
#include <hip/hip_runtime.h>
#include <hip/hip_bf16.h>

// GraphFusion: 3-layer GNN, B=4 N=256 D=128 E=64.
// Exact algebra:
//   eh   = relu(P1_i + P2_j)            P1 = x@w_top + eb1, P2 = x@w_bot
//   mh   = relu(P3_i + eh@W2)           W2 = ew2@mw_bot (precomputed, bf16 frag-major)
//                                       P3 = x@mw_top + mb1 + eb2@mw_bot
//   s_i  = sum_j adj_ij * mh_ij         (fold adjacency BEFORE mw2)
//   msg_i= s_i@mw2 + (sum_j adj_ij)*mb2
//   x    = LN(x + u2(relu(u1(cat(x,msg)))))
// kB: per (b,i) GEMM 256x256x64 on MFMA 16x16x32 bf16, A-frags built in registers.

constexpr int cB = 4, cN = 256, cD = 128, cE = 64, cL = 3, cH = 256; // cH = 2D
#define LN_EPSF 1e-5f

typedef __attribute__((ext_vector_type(8))) short bf8;
typedef __attribute__((ext_vector_type(4))) float f4;

__device__ __forceinline__ ushort f2bf(float f) {  // RNE float->bf16 bits
    uint u = __float_as_uint(f);
    u += 0x7FFFu + ((u >> 16) & 1u);
    return (ushort)(u >> 16);
}

// ---- W2f[l] in MFMA B-fragment-major bf16: frag (ht,kc), lane l, elem e holds
//      W2[k = kc*32 + (l>>4)*8 + e][h = ht*16 + (l&15)].   BS2 = eb2@mw_bot (fp32)
__global__ __launch_bounds__(256) void kW(const float* __restrict__ ew2,
                                          const float* __restrict__ eb2,
                                          const float* __restrict__ mw1,
                                          ushort* __restrict__ W2f,
                                          float* __restrict__ BS2) {
    int l = blockIdx.x, h = threadIdx.x;
    const float* ew2l = ew2 + l * cE * cE;
    const float* eb2l = eb2 + l * cE;
    const float* mbot = mw1 + l * (cD + cE) * cH + cD * cH; // rows D..D+E-1
    float acc[cE];
#pragma unroll
    for (int f = 0; f < cE; ++f) acc[f] = 0.f;
    float bacc = 0.f;
    for (int e = 0; e < cE; ++e) {
        float m = mbot[e * cH + h];
        bacc += eb2l[e] * m;
#pragma unroll
        for (int f = 0; f < cE; ++f) acc[f] += ew2l[f * cE + e] * m;
    }
    ushort* W2fl = W2f + l * cE * cH;
    int ht = h >> 4, hc = h & 15;
#pragma unroll
    for (int f = 0; f < cE; ++f) {
        int kc = f >> 5, lg = (f >> 3) & 3, e = f & 7;
        int lane = lg * 16 + hc;
        W2fl[((ht * 2 + kc) * 64 + lane) * 8 + e] = f2bf(acc[f]);
    }
    BS2[l * cH + h] = bacc;
}

// ---- per-(b,n) precompute P1, P2, P3 from current x. block = 384 (6 waves)
__global__ __launch_bounds__(384) void kA(const float* __restrict__ x,
                                          const float* __restrict__ ew1,
                                          const float* __restrict__ eb1,
                                          const float* __restrict__ mw1,
                                          const float* __restrict__ mb1,
                                          const float* __restrict__ bs2,
                                          float* __restrict__ P1,
                                          float* __restrict__ P2,
                                          float* __restrict__ P3, int l) {
    __shared__ float xs[cD];
    int bn = blockIdx.x, t = threadIdx.x;
    if (t < cD) xs[t] = x[bn * cD + t];
    __syncthreads();
    const float* ew1l = ew1 + l * 2 * cD * cE;
    const float* mw1l = mw1 + l * (cD + cE) * cH;
    if (t < cE) {
        float acc = eb1[l * cE + t];
        for (int d = 0; d < cD; ++d) acc += xs[d] * ew1l[d * cE + t];
        P1[bn * cE + t] = acc;
    } else if (t < 2 * cE) {
        int e = t - cE;
        float acc = 0.f;
        for (int d = 0; d < cD; ++d) acc += xs[d] * ew1l[(cD + d) * cE + e];
        P2[bn * cE + e] = acc;
    } else {
        int h = t - 2 * cE;
        float acc = mb1[l * cH + h] + bs2[l * cH + h];
        for (int d = 0; d < cD; ++d) acc += xs[d] * mw1l[d * cH + h];
        P3[bn * cH + h] = acc;
    }
}

// ---- hot kernel (MFMA): per (b,i), wave w owns j in [64w, 64w+64)
__global__ __launch_bounds__(256, 4) void kB(const float* __restrict__ P1,
                                             const float* __restrict__ P2,
                                             const float* __restrict__ P3,
                                             const float* __restrict__ adj,
                                             const ushort* __restrict__ W2f,
                                             const float* __restrict__ mw2,
                                             const float* __restrict__ mb2,
                                             float* __restrict__ MSG, int l) {
    __shared__ float sS[4][cH];
    __shared__ float sAs[4];
    int bn = blockIdx.x, t = threadIdx.x;
    int w = t >> 6, ln = t & 63, g = ln >> 4, c = ln & 15;
    int b = bn >> 8;
    int jw = w * 64;

    // adjacency values for this lane's 16 rows (replicated across c within group)
    const float* adjr = adj + bn * cN + jw;
    float adjv[4][4];
    float asum = 0.f;
#pragma unroll
    for (int jt = 0; jt < 4; ++jt)
#pragma unroll
        for (int q = 0; q < 4; ++q) {
            float a = adjr[jt * 16 + g * 4 + q];
            adjv[jt][q] = a;
            asum += a;
        }
    asum += __shfl_xor(asum, 16);
    asum += __shfl_xor(asum, 32);

    // P1 fragment pieces (per kc; depend on g via kbase)
    f4 p1lo[2], p1hi[2];
#pragma unroll
    for (int kc = 0; kc < 2; ++kc) {
        const float* p1p = P1 + bn * cE + kc * 32 + g * 8;
        p1lo[kc] = *(const f4*)p1p;
        p1hi[kc] = *(const f4*)(p1p + 4);
    }

    // A fragments in registers: af[jt][kc], lane holds EH[r][kbase..kbase+7] bf16
    bf8 af[4][2];
#pragma unroll
    for (int jt = 0; jt < 4; ++jt) {
        const float* p2r = P2 + (b * cN + jw + jt * 16 + c) * cE;
#pragma unroll
        for (int kc = 0; kc < 2; ++kc) {
            f4 v0 = *(const f4*)(p2r + kc * 32 + g * 8);
            f4 v1 = *(const f4*)(p2r + kc * 32 + g * 8 + 4);
            bf8 a;
#pragma unroll
            for (int e = 0; e < 4; ++e) {
                float x0 = v0[e] + p1lo[kc][e]; x0 = x0 > 0.f ? x0 : 0.f;
                float x1 = v1[e] + p1hi[kc][e]; x1 = x1 > 0.f ? x1 : 0.f;
                a[e]     = (short)f2bf(x0);
                a[e + 4] = (short)f2bf(x1);
            }
            af[jt][kc] = a;
        }
    }

    const ushort* W2l = W2f + l * cE * cH;
    const float* P3r = P3 + bn * cH;
    for (int ht = 0; ht < 16; ++ht) {
        bf8 b0 = *(const bf8*)(W2l + ((ht * 2 + 0) * 64 + ln) * 8);
        bf8 b1 = *(const bf8*)(W2l + ((ht * 2 + 1) * 64 + ln) * 8);
        float p3v = P3r[ht * 16 + c];
        float sp = 0.f;
#pragma unroll
        for (int jt = 0; jt < 4; ++jt) {
            f4 acc = {0.f, 0.f, 0.f, 0.f};
            acc = __builtin_amdgcn_mfma_f32_16x16x32_bf16(af[jt][0], b0, acc, 0, 0, 0);
            acc = __builtin_amdgcn_mfma_f32_16x16x32_bf16(af[jt][1], b1, acc, 0, 0, 0);
#pragma unroll
            for (int q = 0; q < 4; ++q) {
                float mh = p3v + acc[q];           // D[row=jt*16+g*4+q][col=ht*16+c]
                mh = mh > 0.f ? mh : 0.f;
                sp += adjv[jt][q] * mh;
            }
        }
        sp += __shfl_xor(sp, 16);                  // reduce across the 4 lane-groups
        sp += __shfl_xor(sp, 32);
        if (ln < 16) sS[w][ht * 16 + c] = sp;
    }
    if (ln == 0) sAs[w] = asum;
    __syncthreads();
    float stot = sS[0][t] + sS[1][t] + sS[2][t] + sS[3][t];
    sS[0][t] = stot;
    __syncthreads();
    if (t < cD) {
        float at = sAs[0] + sAs[1] + sAs[2] + sAs[3];
        const float* mw2l = mw2 + l * cH * cD;
        float acc = at * mb2[l * cD + t];
#pragma unroll 4
        for (int h = 0; h < cH; ++h) acc += sS[0][h] * mw2l[h * cD + t];
        MSG[bn * cD + t] = acc;
    }
}

// ---- update network + residual + LayerNorm
__global__ __launch_bounds__(256) void kC(float* __restrict__ x,
                                          const float* __restrict__ MSG,
                                          const float* __restrict__ uw1,
                                          const float* __restrict__ ub1,
                                          const float* __restrict__ uw2,
                                          const float* __restrict__ ub2,
                                          const float* __restrict__ lng,
                                          const float* __restrict__ lnb,
                                          float* __restrict__ out, int l, int last) {
    __shared__ float uin[cH];
    __shared__ float uh[cH];
    __shared__ float rs1[4], rs2[4];
    int bn = blockIdx.x, t = threadIdx.x;
    uin[t] = (t < cD) ? x[bn * cD + t] : MSG[bn * cD + (t - cD)];
    __syncthreads();
    const float* uw1l = uw1 + l * cH * cH;
    float acc = ub1[l * cH + t];
    for (int k = 0; k < cH; ++k) acc += uin[k] * uw1l[k * cH + t];
    uh[t] = acc > 0.f ? acc : 0.f;
    __syncthreads();
    float y = 0.f;
    if (t < cD) {
        const float* uw2l = uw2 + l * cH * cD;
        float a2 = ub2[l * cD + t];
        for (int k = 0; k < cH; ++k) a2 += uh[k] * uw2l[k * cD + t];
        y = uin[t] + a2;
    }
    float s1 = y, s2 = y * y;
#pragma unroll
    for (int o = 1; o < 64; o <<= 1) { s1 += __shfl_xor(s1, o); s2 += __shfl_xor(s2, o); }
    if ((t & 63) == 0) { rs1[t >> 6] = s1; rs2[t >> 6] = s2; }
    __syncthreads();
    float tot = rs1[0] + rs1[1] + rs1[2] + rs1[3];
    float tq  = rs2[0] + rs2[1] + rs2[2] + rs2[3];
    float mu  = tot * (1.f / cD);
    float var = tq * (1.f / cD) - mu * mu;
    float inv = rsqrtf(var + LN_EPSF);
    if (t < cD) {
        float res = (y - mu) * inv * lng[l * cD + t] + lnb[l * cD + t];
        x[bn * cD + t] = res;
        if (last) out[bn * cD + t] = res;
    }
}

extern "C" void kernel_launch(void* const* d_in, const int* in_sizes, int n_in,
                              void* d_out, int out_size, void* d_ws, size_t ws_size,
                              hipStream_t stream) {
    (void)in_sizes; (void)n_in; (void)out_size; (void)ws_size;
    const float* nf  = (const float*)d_in[0];
    const float* adj = (const float*)d_in[1];
    const float* ew1 = (const float*)d_in[2];
    const float* eb1 = (const float*)d_in[3];
    const float* ew2 = (const float*)d_in[4];
    const float* eb2 = (const float*)d_in[5];
    const float* mw1 = (const float*)d_in[6];
    const float* mb1 = (const float*)d_in[7];
    const float* mw2 = (const float*)d_in[8];
    const float* mb2 = (const float*)d_in[9];
    const float* uw1 = (const float*)d_in[10];
    const float* ub1 = (const float*)d_in[11];
    const float* uw2 = (const float*)d_in[12];
    const float* ub2 = (const float*)d_in[13];
    const float* lng = (const float*)d_in[14];
    const float* lnb = (const float*)d_in[15];
    float* out = (float*)d_out;

    float* xbuf = (float*)d_ws;                 // B*N*D
    float* P1   = xbuf + cB * cN * cD;          // B*N*E
    float* P2   = P1   + cB * cN * cE;          // B*N*E
    float* P3   = P2   + cB * cN * cE;          // B*N*2D
    float* MSG  = P3   + cB * cN * cH;          // B*N*D
    float* BS2  = MSG  + cB * cN * cD;          // L*2D
    ushort* W2f = (ushort*)(BS2 + cL * cH);     // L*E*2D bf16 (frag-major)

    hipMemcpyAsync(xbuf, nf, cB * cN * cD * sizeof(float),
                   hipMemcpyDeviceToDevice, stream);
    kW<<<cL, 256, 0, stream>>>(ew2, eb2, mw1, W2f, BS2);
    for (int l = 0; l < cL; ++l) {
        kA<<<cB * cN, 384, 0, stream>>>(xbuf, ew1, eb1, mw1, mb1, BS2, P1, P2, P3, l);
        kB<<<cB * cN, 256, 0, stream>>>(P1, P2, P3, adj, W2f, mw2, mb2, MSG, l);
        kC<<<cB * cN, 256, 0, stream>>>(xbuf, MSG, uw1, ub1, uw2, ub2, lng, lnb,
                                        out, l, l == cL - 1);
    }
}

// Round 5
// 160.506 us; speedup vs baseline: 4.2425x; 1.1311x over previous
//
#include <hip/hip_runtime.h>
#include <hip/hip_bf16.h>

// GraphFusion: 3-layer GNN, B=4 N=256 D=128 E=64.
// Exact algebra:
//   eh   = relu(P1_i + P2_j)            P1 = x@w_top + eb1, P2 = x@w_bot
//   mh   = relu(P3_i + eh@W2)           W2 = ew2@mw_bot (precomputed, bf16 frag-major)
//                                       P3 = x@mw_top + mb1 + eb2@mw_bot
//   s_i  = sum_j adj_ij * mh_ij         (fold adjacency BEFORE mw2)
//   msg_i= s_i@mw2 + (sum_j adj_ij)*mb2  (matvec folded into kC; s split over 2 blocks)
//   x    = LN(x + u2(relu(u1(cat(x,msg)))))
// kB: per (b,i,j-half) MFMA 16x16x32 bf16; 2048 blocks for latency hiding.

constexpr int cB = 4, cN = 256, cD = 128, cE = 64, cL = 3, cH = 256; // cH = 2D
#define LN_EPSF 1e-5f

typedef __attribute__((ext_vector_type(8))) short bf8;
typedef __attribute__((ext_vector_type(4))) float f4;

__device__ __forceinline__ ushort f2bf(float f) {  // RNE float->bf16 bits
    uint u = __float_as_uint(f);
    u += 0x7FFFu + ((u >> 16) & 1u);
    return (ushort)(u >> 16);
}

// ---- W2f[l] in MFMA B-fragment-major bf16: frag (ht,kc), lane l, elem e holds
//      W2[k = kc*32 + (l>>4)*8 + e][h = ht*16 + (l&15)].   BS2 = eb2@mw_bot (fp32)
// grid = cL*8 blocks: block handles one (layer, f-octet). acc[8] stays in VGPRs.
__global__ __launch_bounds__(256) void kW(const float* __restrict__ ew2,
                                          const float* __restrict__ eb2,
                                          const float* __restrict__ mw1,
                                          ushort* __restrict__ W2f,
                                          float* __restrict__ BS2) {
    int bx = blockIdx.x, l = bx >> 3, f0 = (bx & 7) * 8;
    int h = threadIdx.x;
    const float* ew2l = ew2 + l * cE * cE;
    const float* eb2l = eb2 + l * cE;
    const float* mbot = mw1 + l * (cD + cE) * cH + cD * cH; // rows D..D+E-1
    float acc[8];
#pragma unroll
    for (int f = 0; f < 8; ++f) acc[f] = 0.f;
    float bacc = 0.f;
    for (int e = 0; e < cE; ++e) {
        float m = mbot[e * cH + h];       // coalesced across h
        if (f0 == 0) bacc += eb2l[e] * m;
#pragma unroll
        for (int f = 0; f < 8; ++f) acc[f] += ew2l[(f0 + f) * cE + e] * m;
    }
    ushort* W2fl = W2f + l * cE * cH;
    int ht = h >> 4, hc = h & 15;
#pragma unroll
    for (int f = 0; f < 8; ++f) {
        int ff = f0 + f;
        int kc = ff >> 5, lg = (ff >> 3) & 3, e = ff & 7;
        W2fl[((ht * 2 + kc) * 64 + lg * 16 + hc) * 8 + e] = f2bf(acc[f]);
    }
    if (f0 == 0) BS2[l * cH + h] = bacc;
}

// ---- per-(b,n) precompute P1, P2, P3 from current x. block = 384 (6 waves)
__global__ __launch_bounds__(384) void kA(const float* __restrict__ x,
                                          const float* __restrict__ ew1,
                                          const float* __restrict__ eb1,
                                          const float* __restrict__ mw1,
                                          const float* __restrict__ mb1,
                                          const float* __restrict__ bs2,
                                          float* __restrict__ P1,
                                          float* __restrict__ P2,
                                          float* __restrict__ P3, int l) {
    __shared__ float xs[cD];
    int bn = blockIdx.x, t = threadIdx.x;
    if (t < cD) xs[t] = x[bn * cD + t];
    __syncthreads();
    const float* ew1l = ew1 + l * 2 * cD * cE;
    const float* mw1l = mw1 + l * (cD + cE) * cH;
    if (t < cE) {
        float acc = eb1[l * cE + t];
        for (int d = 0; d < cD; ++d) acc += xs[d] * ew1l[d * cE + t];
        P1[bn * cE + t] = acc;
    } else if (t < 2 * cE) {
        int e = t - cE;
        float acc = 0.f;
        for (int d = 0; d < cD; ++d) acc += xs[d] * ew1l[(cD + d) * cE + e];
        P2[bn * cE + e] = acc;
    } else {
        int h = t - 2 * cE;
        float acc = mb1[l * cH + h] + bs2[l * cH + h];
        for (int d = 0; d < cD; ++d) acc += xs[d] * mw1l[d * cH + h];
        P3[bn * cH + h] = acc;
    }
}

// ---- hot kernel (MFMA): block = (b,i, j-half); wave w owns j in [half*128+32w, +32)
// Writes partial s-vector (256) and partial adj-row-sum; kC finishes the matvec.
__global__ __launch_bounds__(256, 8) void kB(const float* __restrict__ P1,
                                             const float* __restrict__ P2,
                                             const float* __restrict__ P3,
                                             const float* __restrict__ adj,
                                             const ushort* __restrict__ W2f,
                                             float* __restrict__ Sp,
                                             float* __restrict__ AsumP, int l) {
    __shared__ float sP3[cH];
    __shared__ float sS[4][cH];
    __shared__ float sAs[4];
    int bx = blockIdx.x, bn = bx >> 1, half = bx & 1;
    int t = threadIdx.x, w = t >> 6, ln = t & 63, g = ln >> 4, c = ln & 15;
    int b = bn >> 8;
    int jw = half * 128 + w * 32;

    sP3[t] = P3[bn * cH + t];

    // adjacency values for this lane's rows (replicated across c within group)
    const float* adjr = adj + bn * cN + jw;
    float adjv[2][4];
    float asum = 0.f;
#pragma unroll
    for (int jt = 0; jt < 2; ++jt)
#pragma unroll
        for (int q = 0; q < 4; ++q) {
            float a = adjr[jt * 16 + g * 4 + q];
            adjv[jt][q] = a;
            asum += a;
        }
    asum += __shfl_xor(asum, 16);
    asum += __shfl_xor(asum, 32);

    // P1 fragment pieces (depend on g,kc)
    const float* p1p = P1 + bn * cE;
    f4 p1lo[2], p1hi[2];
#pragma unroll
    for (int kc = 0; kc < 2; ++kc) {
        p1lo[kc] = *(const f4*)(p1p + kc * 32 + g * 8);
        p1hi[kc] = *(const f4*)(p1p + kc * 32 + g * 8 + 4);
    }

    // A fragments in registers: af[jt][kc]; lane holds EH[row][kbase..kbase+7] bf16
    bf8 af[2][2];
#pragma unroll
    for (int jt = 0; jt < 2; ++jt) {
        const float* p2r = P2 + (b * cN + jw + jt * 16 + c) * cE;
#pragma unroll
        for (int kc = 0; kc < 2; ++kc) {
            f4 v0 = *(const f4*)(p2r + kc * 32 + g * 8);
            f4 v1 = *(const f4*)(p2r + kc * 32 + g * 8 + 4);
            bf8 a;
#pragma unroll
            for (int e = 0; e < 4; ++e) {
                float x0 = v0[e] + p1lo[kc][e]; x0 = x0 > 0.f ? x0 : 0.f;
                float x1 = v1[e] + p1hi[kc][e]; x1 = x1 > 0.f ? x1 : 0.f;
                a[e]     = (short)f2bf(x0);
                a[e + 4] = (short)f2bf(x1);
            }
            af[jt][kc] = a;
        }
    }
    __syncthreads();   // sP3 ready

    const ushort* W2l = W2f + l * cE * cH;
    for (int ht = 0; ht < 16; ++ht) {
        bf8 b0 = *(const bf8*)(W2l + ((ht * 2 + 0) * 64 + ln) * 8);
        bf8 b1 = *(const bf8*)(W2l + ((ht * 2 + 1) * 64 + ln) * 8);
        float p3v = sP3[ht * 16 + c];
        float sp = 0.f;
#pragma unroll
        for (int jt = 0; jt < 2; ++jt) {
            f4 acc = {0.f, 0.f, 0.f, 0.f};
            acc = __builtin_amdgcn_mfma_f32_16x16x32_bf16(af[jt][0], b0, acc, 0, 0, 0);
            acc = __builtin_amdgcn_mfma_f32_16x16x32_bf16(af[jt][1], b1, acc, 0, 0, 0);
#pragma unroll
            for (int q = 0; q < 4; ++q) {
                float mh = p3v + acc[q];           // D[row=jt*16+g*4+q][col=ht*16+c]
                mh = mh > 0.f ? mh : 0.f;
                sp += adjv[jt][q] * mh;
            }
        }
        sp += __shfl_xor(sp, 16);                  // reduce across the 4 lane-groups
        sp += __shfl_xor(sp, 32);
        if (ln < 16) sS[w][ht * 16 + c] = sp;
    }
    if (ln == 0) sAs[w] = asum;
    __syncthreads();
    Sp[bx * cH + t] = sS[0][t] + sS[1][t] + sS[2][t] + sS[3][t];
    if (t == 0) AsumP[bx] = sAs[0] + sAs[1] + sAs[2] + sAs[3];
}

// ---- message matvec + update network + residual + LayerNorm
__global__ __launch_bounds__(256) void kC(float* __restrict__ x,
                                          const float* __restrict__ Sp,
                                          const float* __restrict__ AsumP,
                                          const float* __restrict__ mw2,
                                          const float* __restrict__ mb2,
                                          const float* __restrict__ uw1,
                                          const float* __restrict__ ub1,
                                          const float* __restrict__ uw2,
                                          const float* __restrict__ ub2,
                                          const float* __restrict__ lng,
                                          const float* __restrict__ lnb,
                                          float* __restrict__ out, int l, int last) {
    __shared__ float sS[cH];
    __shared__ float pM[cH];
    __shared__ float uin[cH];
    __shared__ float uh[cH];
    __shared__ float rs1[4], rs2[4];
    int bn = blockIdx.x, t = threadIdx.x;
    sS[t] = Sp[(2 * bn) * cH + t] + Sp[(2 * bn + 1) * cH + t];
    __syncthreads();
    float atot = AsumP[2 * bn] + AsumP[2 * bn + 1];
    // matvec: msg[d] = sum_h sS[h]*mw2[h][d] + atot*mb2[d]; 256 thr on (d, h-half)
    {
        int d = t & 127, hh = t >> 7;
        const float* mw2l = mw2 + l * cH * cD;
        float p = 0.f;
#pragma unroll 8
        for (int h = hh * 128; h < hh * 128 + 128; ++h) p += sS[h] * mw2l[h * cD + d];
        pM[t] = p;
    }
    __syncthreads();
    uin[t] = (t < cD) ? x[bn * cD + t]
                      : (pM[t - cD] + pM[t - cD + 128] + atot * mb2[l * cD + (t - cD)]);
    __syncthreads();
    const float* uw1l = uw1 + l * cH * cH;
    float acc = ub1[l * cH + t];
    for (int k = 0; k < cH; ++k) acc += uin[k] * uw1l[k * cH + t];
    uh[t] = acc > 0.f ? acc : 0.f;
    __syncthreads();
    float y = 0.f;
    if (t < cD) {
        const float* uw2l = uw2 + l * cH * cD;
        float a2 = ub2[l * cD + t];
        for (int k = 0; k < cH; ++k) a2 += uh[k] * uw2l[k * cD + t];
        y = uin[t] + a2;
    }
    float s1 = y, s2 = y * y;
#pragma unroll
    for (int o = 1; o < 64; o <<= 1) { s1 += __shfl_xor(s1, o); s2 += __shfl_xor(s2, o); }
    if ((t & 63) == 0) { rs1[t >> 6] = s1; rs2[t >> 6] = s2; }
    __syncthreads();
    float tot = rs1[0] + rs1[1] + rs1[2] + rs1[3];
    float tq  = rs2[0] + rs2[1] + rs2[2] + rs2[3];
    float mu  = tot * (1.f / cD);
    float var = tq * (1.f / cD) - mu * mu;
    float inv = rsqrtf(var + LN_EPSF);
    if (t < cD) {
        float res = (y - mu) * inv * lng[l * cD + t] + lnb[l * cD + t];
        x[bn * cD + t] = res;
        if (last) out[bn * cD + t] = res;
    }
}

extern "C" void kernel_launch(void* const* d_in, const int* in_sizes, int n_in,
                              void* d_out, int out_size, void* d_ws, size_t ws_size,
                              hipStream_t stream) {
    (void)in_sizes; (void)n_in; (void)out_size; (void)ws_size;
    const float* nf  = (const float*)d_in[0];
    const float* adj = (const float*)d_in[1];
    const float* ew1 = (const float*)d_in[2];
    const float* eb1 = (const float*)d_in[3];
    const float* ew2 = (const float*)d_in[4];
    const float* eb2 = (const float*)d_in[5];
    const float* mw1 = (const float*)d_in[6];
    const float* mb1 = (const float*)d_in[7];
    const float* mw2 = (const float*)d_in[8];
    const float* mb2 = (const float*)d_in[9];
    const float* uw1 = (const float*)d_in[10];
    const float* ub1 = (const float*)d_in[11];
    const float* uw2 = (const float*)d_in[12];
    const float* ub2 = (const float*)d_in[13];
    const float* lng = (const float*)d_in[14];
    const float* lnb = (const float*)d_in[15];
    float* out = (float*)d_out;

    float* xbuf  = (float*)d_ws;                 // B*N*D
    float* P1    = xbuf + cB * cN * cD;          // B*N*E
    float* P2    = P1   + cB * cN * cE;          // B*N*E
    float* P3    = P2   + cB * cN * cE;          // B*N*2D
    float* Sp    = P3   + cB * cN * cH;          // 2*B*N*2D (partial s, per j-half)
    float* AsumP = Sp   + 2 * cB * cN * cH;      // 2*B*N
    float* BS2   = AsumP + 2 * cB * cN;          // L*2D
    ushort* W2f  = (ushort*)(BS2 + cL * cH);     // L*E*2D bf16 (frag-major)

    hipMemcpyAsync(xbuf, nf, cB * cN * cD * sizeof(float),
                   hipMemcpyDeviceToDevice, stream);
    kW<<<cL * 8, 256, 0, stream>>>(ew2, eb2, mw1, W2f, BS2);
    for (int l = 0; l < cL; ++l) {
        kA<<<cB * cN, 384, 0, stream>>>(xbuf, ew1, eb1, mw1, mb1, BS2, P1, P2, P3, l);
        kB<<<cB * cN * 2, 256, 0, stream>>>(P1, P2, P3, adj, W2f, Sp, AsumP, l);
        kC<<<cB * cN, 256, 0, stream>>>(xbuf, Sp, AsumP, mw2, mb2, uw1, ub1, uw2, ub2,
                                        lng, lnb, out, l, l == cL - 1);
    }
}